// Round 8
// baseline (98.808 us; speedup 1.0000x reference)
//
#include <hip/hip_runtime.h>
#include <hip/hip_fp16.h>

#define NQ   13
#define DIM  8192
#define PI_F 3.14159265358979323846f
#define NT   256     // 4 waves/block; grid 512 -> 2 blocks/CU
#define NAMP 32      // amplitudes per thread (5 register bits)

// Register-resident state. Index map: i = (j<<8) | (w<<6) | tl
//   j  = amp register index, 5 bits  -> i bits 8..12 (qubits 4..0)
//   w  = wave id, 2 bits (w0,w1)     -> i bits 6,7   (qubits 6,5)
//   tl = lane, 6 bits                -> i bits 0..5  (qubits 12..7)
// Lane-bit gates: masks 1,2,8 via DPP (proven R3/R6); 4,16,32 via shfl_xor
// (proven R1). Wave-bit gates: 12 exchanges via one LDS buffer using the
// R0-proven 36-stride b128 layout. No other LDS state traffic.
__device__ __forceinline__ int base0(int t) { return 36 * t; }
#define NSLOT 9216   // 256 threads x 36 half2 slots

union F4H { float4 f; __half2 h[4]; };

__device__ __forceinline__ void rsincos(float x, float* s, float* c) {
  const float INV2PI = 0.15915494309189535f;
  const float TWOPI  = 6.283185307179586f;
  float r = x * INV2PI;
  r -= rintf(r);
  float ang = r * TWOPI;
  *s = __sinf(ang);
  *c = __cosf(ang);
}

__device__ __forceinline__ float2 cphase(float2 v, float cs, float sn) {
  return make_float2(fmaf(cs, v.x, -sn * v.y), fmaf(cs, v.y, sn * v.x));
}
__device__ __forceinline__ float2 cmul(float2 a, float2 b) {
  return make_float2(fmaf(a.x, b.x, -a.y * b.y), fmaf(a.x, b.y, a.y * b.x));
}

// ---- cross-lane partner: DPP for masks 1,2,8; ds_bpermute (shfl) for 4,16,32
template<int MASK>
__device__ __forceinline__ __half2 lanePartner(__half2 v) {
  union { __half2 h; int i; } u, r; u.h = v;
  if constexpr (MASK == 1)
    r.i = __builtin_amdgcn_update_dpp(u.i, u.i, 0xB1, 0xF, 0xF, false);  // [1,0,3,2]
  else if constexpr (MASK == 2)
    r.i = __builtin_amdgcn_update_dpp(u.i, u.i, 0x4E, 0xF, 0xF, false);  // [2,3,0,1]
  else if constexpr (MASK == 8)
    r.i = __builtin_amdgcn_update_dpp(u.i, u.i, 0x128, 0xF, 0xF, false); // row_ror:8
  else
    r.i = __shfl_xor(u.i, MASK, 64);
  return r.h;
}

// ---- exchange-buffer access (R0-proven 8x b128 at 36-stride)
__device__ __forceinline__ void loadXh(const __half2* __restrict__ sAmp, int t, __half2* amp) {
  const __half2* p = sAmp + base0(t);
  #pragma unroll
  for (int k = 0; k < 8; k++) {
    F4H u; u.f = *reinterpret_cast<const float4*>(p + 4 * k);
    #pragma unroll
    for (int c = 0; c < 4; c++) amp[4 * k + c] = u.h[c];
  }
}
__device__ __forceinline__ void storeXh(__half2* __restrict__ sAmp, int t, const __half2* amp) {
  __half2* p = sAmp + base0(t);
  #pragma unroll
  for (int k = 0; k < 8; k++) {
    F4H u;
    #pragma unroll
    for (int c = 0; c < 4; c++) u.h[c] = amp[4 * k + c];
    *reinterpret_cast<float4*>(p + 4 * k) = u.f;
  }
}

// ---- fp16 register-bit gates (R0/R6-verified)
template<int KB>
__device__ __forceinline__ void fwht_bitH(__half2* amp) {
  #pragma unroll
  for (int j = 0; j < NAMP; j++) if (!(j & (1 << KB))) {
    int j1 = j | (1 << KB);
    __half2 a0 = amp[j], a1 = amp[j1];
    amp[j]  = __hadd2(a0, a1);
    amp[j1] = __hsub2(a0, a1);
  }
}
template<int KB>
__device__ __forceinline__ void applyRyH(__half2* amp, __half2 nta, __half2 sa) {
  #pragma unroll
  for (int j = 0; j < NAMP; j++) if (!(j & (1 << KB))) {
    int j1 = j | (1 << KB);
    amp[j]  = __hfma2(nta, amp[j1], amp[j]);
    amp[j1] = __hfma2(sa,  amp[j],  amp[j1]);
    amp[j]  = __hfma2(nta, amp[j1], amp[j]);
  }
}
// ---- fp16 lane-bit gates (R1/R3/R6-verified math)
template<int MASK>
__device__ __forceinline__ void laneRyH(__half2* amp, __half2 c2, __half2 spm) {
  #pragma unroll
  for (int j = 0; j < NAMP; j++) {
    __half2 p = lanePartner<MASK>(amp[j]);
    amp[j] = __hfma2(spm, p, __hmul2(c2, amp[j]));
  }
}
template<int MASK>
__device__ __forceinline__ void laneFwhtH(__half2* amp, __half2 sgn) {
  #pragma unroll
  for (int j = 0; j < NAMP; j++) {
    __half2 p = lanePartner<MASK>(amp[j]);
    amp[j] = __hfma2(sgn, amp[j], p);
  }
}

// psi *= exp(i*phi(i)); phi = u + 0.5*(v^2 - A2). Tree over j bits 8..11,
// +w[12] fold for j4; base over (tl,w) bits 0..7. INIT writes unit phase.
template<bool INIT>
__device__ __forceinline__ void featureDiag(__half2* amp,
                                            const float* __restrict__ wXp,
                                            const float* __restrict__ wAp,
                                            const float* __restrict__ consp,
                                            int tl, int w0, int w1) {
  float u16[16], v16[16];
  float ub = consp[0], vb = consp[1];
  #pragma unroll
  for (int k = 0; k < 6; k++) if ((tl >> k) & 1) { ub += wXp[k]; vb += wAp[k]; }
  if (w0) { ub += wXp[6]; vb += wAp[6]; }
  if (w1) { ub += wXp[7]; vb += wAp[7]; }
  u16[0] = ub; v16[0] = vb;
  #pragma unroll
  for (int k = 0; k < 4; k++) {
    float wu = wXp[8 + k], wv = wAp[8 + k];
    #pragma unroll
    for (int m = 0; m < (1 << k); m++) {
      u16[m | (1 << k)] = u16[m] + wu;
      v16[m | (1 << k)] = v16[m] + wv;
    }
  }
  const float du = wXp[12], dv = wAp[12], A2 = consp[2];
  #pragma unroll
  for (int j = 0; j < NAMP; j++) {
    float uu = u16[j & 15] + ((j >> 4) ? du : 0.0f);
    float vv = v16[j & 15] + ((j >> 4) ? dv : 0.0f);
    float phi = uu + 0.5f * (vv * vv - A2);
    float sn, cs; rsincos(phi, &sn, &cs);
    if constexpr (INIT) {
      amp[j] = __float22half2_rn(make_float2(cs, sn));
    } else {
      float2 a = __half22float2(amp[j]);
      amp[j] = __float22half2_rn(cphase(a, cs, sn));
    }
  }
}

// psi *= ENT(i)*exp(i*rho(i)): Rz_l + ENT. Sign-folded (R6 applyDiagL
// skeleton, re-derived for this layout):
//  pairs(0..4): popc(tl&(tl>>1)); (5,6): tl5&w0; (6,7): w0&w1 -> c[0] sign
//  (7,8): w1&j0 -> negate e8; (8,9),(9,10),(10,11): tree folds;
//  (11,12): j3&j4 -> +/-e12 on the hi half.
__device__ __forceinline__ void applyDiag(__half2* amp,
                                          const float* __restrict__ wb,
                                          const float* __restrict__ eR,
                                          const float* __restrict__ eI,
                                          float bias, int tl, int w0, int w1) {
  float base = bias;
  #pragma unroll
  for (int k = 0; k < 6; k++) if ((tl >> k) & 1) base += wb[k];
  if (w0) base += wb[6];
  if (w1) base += wb[7];
  float2 c[16];
  { float sn, cs; rsincos(base, &sn, &cs);
    int sg = (__popc(tl & (tl >> 1)) ^ (((tl >> 5) & 1) & w0) ^ (w0 & w1)) & 1;
    float s = sg ? -1.0f : 1.0f;
    c[0] = make_float2(cs * s, sn * s); }
  { float2 e0 = make_float2(eR[8], eI[8]);
    if (w1) { e0.x = -e0.x; e0.y = -e0.y; }
    c[1] = cmul(c[0], e0); }
  #pragma unroll
  for (int k = 1; k < 4; k++) {
    float2 ep = make_float2(eR[8 + k], eI[8 + k]);
    float2 em = make_float2(-ep.x, -ep.y);
    #pragma unroll
    for (int m = 0; m < (1 << k); m++)
      c[m | (1 << k)] = cmul(c[m], ((m >> (k - 1)) & 1) ? em : ep);
  }
  #pragma unroll
  for (int j = 0; j < 16; j++) {
    float2 a = __half22float2(amp[j]);
    amp[j] = __float22half2_rn(cphase(a, c[j].x, c[j].y));
  }
  float2 e4  = make_float2(eR[12], eI[12]);
  float2 e4m = make_float2(-e4.x, -e4.y);
  #pragma unroll
  for (int j = 16; j < 32; j++) {
    float2 cc = cmul(c[j - 16], (((j - 16) >> 3) & 1) ? e4m : e4);
    float2 a = __half22float2(amp[j]);
    amp[j] = __float22half2_rn(cphase(a, cc.x, cc.y));
  }
}

// (256,1): lifted VGPR cap; grid 512 -> 2 blocks/CU.
__global__ __launch_bounds__(NT, 1) void qc_kernel(
    const float* __restrict__ xin,
    const float* __restrict__ thin,
    const float* __restrict__ bin,
    float* __restrict__ out) {
  __shared__ alignas(16) __half2 sEx[NSLOT];   // exchange buffer only
  __shared__ __half2 hNTA[65], hSA[65];   // fp16 shear (-ta,-ta),(sa,sa), l*13+q
  __shared__ __half2 hC2[65], hS2[65];    // fp16 rotation (c,c),(s,s), l*13+q
  __shared__ float gBbit[65];             // Rz b by [l*13 + bitpos], bitpos = 12-q
  __shared__ float eBr[65], eBi[65];      // cos(b), sin(b) by [l*13 + bitpos]
  __shared__ float wX[13], wA[13];        // -2x, -2a by bitpos
  __shared__ float cons[8];               // 0:X 1:A 2:A2 3..7:-0.5*sum b_l
  __shared__ float red[NT / 64];

  const int t  = threadIdx.x;
  const int tl = t & 63;
  const int w0 = (t >> 6) & 1;
  const int w1 = (t >> 7) & 1;
  const int b  = blockIdx.x;

  if (t < NQ) {
    float xq = xin[b * NQ + t];
    float aq = PI_F - xq;
    wX[12 - t] = -2.0f * xq;
    wA[12 - t] = -2.0f * aq;
  }
  if (t < 65) {
    float av = thin[2 * t];
    float bv = thin[2 * t + 1];
    float ca = cosf(0.5f * av);
    float sa = sinf(0.5f * av);
    float ta = sa / (1.0f + ca);
    hNTA[t] = __float2half2_rn(-ta);
    hSA[t]  = __float2half2_rn(sa);
    hC2[t]  = __float2half2_rn(ca);
    hS2[t]  = __float2half2_rn(sa);
    int l = t / NQ, q = t % NQ;
    int s = l * NQ + (12 - q);
    gBbit[s] = bv;
    eBr[s] = cosf(bv);
    eBi[s] = sinf(bv);
  }
  __syncthreads();
  if (t == 0) {
    float X = 0.f, A = 0.f, A2 = 0.f;
    for (int p = 0; p < NQ; p++) {
      float xq = -0.5f * wX[p], aq = -0.5f * wA[p];
      X += xq; A += aq; A2 += aq * aq;
    }
    cons[0] = X; cons[1] = A; cons[2] = A2;
    for (int l = 0; l < 5; l++) {
      float s = 0.f;
      for (int p = 0; p < NQ; p++) s += gBbit[l * NQ + p];
      cons[3 + l] = -0.5f * s;
    }
  }
  __syncthreads();

  __half2 amp[NAMP];
  const __half2 P1 = __float2half2_rn(1.0f), M1 = __float2half2_rn(-1.0f);

  // wave-bit exchange helpers (straight-line, barrier-bracketed)
  auto exchFwht = [&](int bit) {          // FWHT on wave bit: a' = sgn*me + p
    __syncthreads();
    storeXh(sEx, t, amp);
    __syncthreads();
    __half2 p[NAMP];
    loadXh(sEx, t ^ (64 << bit), p);
    int wb = bit ? w1 : w0;
    __half2 sgn = wb ? M1 : P1;
    #pragma unroll
    for (int j = 0; j < NAMP; j++) amp[j] = __hfma2(sgn, amp[j], p[j]);
  };
  auto exchRy = [&](int bit, int gq) {    // Ry on wave bit: a' = c*me +/- s*p
    __syncthreads();
    storeXh(sEx, t, amp);
    __syncthreads();
    __half2 p[NAMP];
    loadXh(sEx, t ^ (64 << bit), p);
    int wb = bit ? w1 : w0;
    __half2 c2 = hC2[gq], s2 = hS2[gq];
    __half2 spm = wb ? s2 : __hneg2(s2);
    #pragma unroll
    for (int j = 0; j < NAMP; j++)
      amp[j] = __hfma2(spm, p[j], __hmul2(c2, amp[j]));
  };

  // ---- init: psi = exp(i*phi1)
  featureDiag<true>(amp, wX, wA, cons, tl, w0, w1);

  // ---- FWHT, all 13 bits: reg (j bits), lane (tl bits), wave (w bits)
  fwht_bitH<0>(amp); fwht_bitH<1>(amp); fwht_bitH<2>(amp);
  fwht_bitH<3>(amp); fwht_bitH<4>(amp);
  laneFwhtH<1>(amp,  (tl & 1)  ? M1 : P1);
  laneFwhtH<2>(amp,  (tl & 2)  ? M1 : P1);
  laneFwhtH<4>(amp,  (tl & 4)  ? M1 : P1);
  laneFwhtH<8>(amp,  (tl & 8)  ? M1 : P1);
  laneFwhtH<16>(amp, (tl & 16) ? M1 : P1);
  laneFwhtH<32>(amp, (tl & 32) ? M1 : P1);
  exchFwht(0);
  exchFwht(1);

  // ---- second feature diagonal
  featureDiag<false>(amp, wX, wA, cons, tl, w0, w1);

  // ---- layers: 13 Ry gates each; diag between layers; readout after L4
  float acc = 0.0f;
  for (int l = 0; l < 5; ++l) {
    const int g = l * NQ;
    // register bits: qubits 0..4 (j bits 4..0)
    applyRyH<4>(amp, hNTA[g + 0], hSA[g + 0]);
    applyRyH<3>(amp, hNTA[g + 1], hSA[g + 1]);
    applyRyH<2>(amp, hNTA[g + 2], hSA[g + 2]);
    applyRyH<1>(amp, hNTA[g + 3], hSA[g + 3]);
    applyRyH<0>(amp, hNTA[g + 4], hSA[g + 4]);
    // lane bits: qubits 12..7 (masks 1,2,4,8,16,32)
    { __half2 s2 = hS2[g + 12]; laneRyH<1>(amp,  hC2[g + 12], (tl & 1)  ? s2 : __hneg2(s2)); }
    { __half2 s2 = hS2[g + 11]; laneRyH<2>(amp,  hC2[g + 11], (tl & 2)  ? s2 : __hneg2(s2)); }
    { __half2 s2 = hS2[g + 10]; laneRyH<4>(amp,  hC2[g + 10], (tl & 4)  ? s2 : __hneg2(s2)); }
    { __half2 s2 = hS2[g + 9];  laneRyH<8>(amp,  hC2[g + 9],  (tl & 8)  ? s2 : __hneg2(s2)); }
    { __half2 s2 = hS2[g + 8];  laneRyH<16>(amp, hC2[g + 8],  (tl & 16) ? s2 : __hneg2(s2)); }
    { __half2 s2 = hS2[g + 7];  laneRyH<32>(amp, hC2[g + 7],  (tl & 32) ? s2 : __hneg2(s2)); }
    // wave bits: qubit 6 (w0), qubit 5 (w1)
    exchRy(0, g + 6);
    exchRy(1, g + 5);
    if (l < 4) {
      applyDiag(amp, gBbit + g, eBr + g, eBi + g, cons[3 + l], tl, w0, w1);
    } else {
      // readout: trailing Rz_4 invisible in |amp|^2; parity (-1)^popc(i)
      int pt = __popc(t) & 1;     // covers tl, w0, w1 bits
      #pragma unroll
      for (int j = 0; j < NAMP; j++) {
        float2 a = __half22float2(amp[j]);
        float p2 = fmaf(a.x, a.x, a.y * a.y);
        acc += ((pt + __popc(j)) & 1) ? -p2 : p2;
      }
    }
  }

  // block reduction (raw scale 2^26)
  #pragma unroll
  for (int off = 32; off > 0; off >>= 1) acc += __shfl_down(acc, off, 64);
  if ((t & 63) == 0) red[t >> 6] = acc;
  __syncthreads();
  if (t == 0) {
    float total = red[0] + red[1] + red[2] + red[3];
    float logit = total * (1.0f / 67108864.0f) + bin[0];
    out[b * 2 + 0] = -logit;
    out[b * 2 + 1] = logit;
  }
}

extern "C" void kernel_launch(void* const* d_in, const int* in_sizes, int n_in,
                              void* d_out, int out_size, void* d_ws, size_t ws_size,
                              hipStream_t stream) {
  const float* x  = (const float*)d_in[0];
  const float* th = (const float*)d_in[1];
  const float* bi = (const float*)d_in[2];
  float* out = (float*)d_out;
  int B = in_sizes[0] / NQ;   // 512
  qc_kernel<<<B, NT, 0, stream>>>(x, th, bi, out);
}

// Round 9
// 90.305 us; speedup vs baseline: 1.0941x; 1.0941x over previous
//
#include <hip/hip_runtime.h>
#include <hip/hip_fp16.h>

#define NQ   13
#define DIM  8192
#define PI_F 3.14159265358979323846f
#define NT   256     // 4 waves/block; grid 512 -> 2 blocks/CU
#define NAMP 32      // amplitudes per thread (5-bit register window)
#define NSLOT 9216   // global layout L(i) = i + 4*(i>>5) (half2 slots)

// Pattern H: i = (t<<5)|j. reg j bits = i0..i4 (q12..q8); lane t0,t1,t3 ->
//   i5,i6,i8 (q7,q6,q4) via DPP masks 1,2,8; t2,t4 -> i7,i9 via shfl masks
//   4,16 (FWHT only); t5 -> i10 (ungated in H); wave t6,t7 -> i11,i12.
//   32 contiguous slots -> 8x b128 (proven R0..R6).
// Pattern C: i = (g<<10) | fC(t) | c, amp j = (g<<2)|c. reg j0,j1 = i0,i1
//   (held, gated in H); j2,j3,j4 = i10,i11,i12 (q2,q1,q0). Lane t0,t1 ->
//   i7,i9 (q5,q3) via DPP masks 1,2. fC: t0->i7, t1->i9, t2..t6->i2..i6,
//   t7->i8. 8 runs of 4 slots -> 8x b128; hand-verified uniform 8 lanes per
//   4-bank group = the 1024B/wave floor (conflict-free).
__device__ __forceinline__ int baseH(int t) { return 36 * t; }
__device__ __forceinline__ int fC(int t) {
  return ((t & 1) << 7) | (((t >> 1) & 1) << 9) | (((t >> 2) & 0x1F) << 2)
       | (((t >> 7) & 1) << 8);
}

union F4H { float4 f; __half2 h[4]; };

__device__ __forceinline__ void rsincos(float x, float* s, float* c) {
  const float INV2PI = 0.15915494309189535f;
  const float TWOPI  = 6.283185307179586f;
  float r = x * INV2PI;
  r -= rintf(r);
  float ang = r * TWOPI;
  *s = __sinf(ang);
  *c = __cosf(ang);
}

// ---- fp32 helpers
__device__ __forceinline__ float2 f2add(float2 a, float2 b) {
  return make_float2(a.x + b.x, a.y + b.y);
}
__device__ __forceinline__ float2 f2sub(float2 a, float2 b) {
  return make_float2(a.x - b.x, a.y - b.y);
}
__device__ __forceinline__ float2 cphase(float2 v, float cs, float sn) {
  return make_float2(fmaf(cs, v.x, -sn * v.y), fmaf(cs, v.y, sn * v.x));
}
__device__ __forceinline__ float2 cmul(float2 a, float2 b) {
  return make_float2(fmaf(a.x, b.x, -a.y * b.y), fmaf(a.x, b.y, a.y * b.x));
}

// ---- cross-lane partner: DPP masks 1,2 (quad_perm), 8 (row_ror:8) — all
// proven R3/R5/R6; masks 4,16 via shfl_xor (proven R7; FWHT-only here).
template<int MASK>
__device__ __forceinline__ __half2 lanePartner(__half2 v) {
  union { __half2 h; int i; } u, r; u.h = v;
  if constexpr (MASK == 1)
    r.i = __builtin_amdgcn_update_dpp(u.i, u.i, 0xB1, 0xF, 0xF, false);  // [1,0,3,2]
  else if constexpr (MASK == 2)
    r.i = __builtin_amdgcn_update_dpp(u.i, u.i, 0x4E, 0xF, 0xF, false);  // [2,3,0,1]
  else if constexpr (MASK == 8)
    r.i = __builtin_amdgcn_update_dpp(u.i, u.i, 0x128, 0xF, 0xF, false); // row_ror:8
  else
    r.i = __shfl_xor(u.i, MASK, 64);
  return r.h;
}

// ---- LDS access, H pattern (8x b128; proven)
__device__ __forceinline__ void loadHh(const __half2* __restrict__ sAmp, int t, __half2* amp) {
  const __half2* p = sAmp + baseH(t);
  #pragma unroll
  for (int k = 0; k < 8; k++) {
    F4H u; u.f = *reinterpret_cast<const float4*>(p + 4 * k);
    #pragma unroll
    for (int c = 0; c < 4; c++) amp[4 * k + c] = u.h[c];
  }
}
__device__ __forceinline__ void storeHh(__half2* __restrict__ sAmp, int t, const __half2* amp) {
  __half2* p = sAmp + baseH(t);
  #pragma unroll
  for (int k = 0; k < 8; k++) {
    F4H u;
    #pragma unroll
    for (int c = 0; c < 4; c++) u.h[c] = amp[4 * k + c];
    *reinterpret_cast<float4*>(p + 4 * k) = u.f;
  }
}
// ---- LDS access, C pattern (8x b128 at stride 1152, base cpad = L(fC(t)))
__device__ __forceinline__ void loadCh(const __half2* __restrict__ sAmp, int cpad, __half2* amp) {
  const __half2* p = sAmp + cpad;
  #pragma unroll
  for (int g = 0; g < 8; g++) {
    F4H u; u.f = *reinterpret_cast<const float4*>(p + 1152 * g);
    #pragma unroll
    for (int c = 0; c < 4; c++) amp[4 * g + c] = u.h[c];
  }
}
__device__ __forceinline__ void storeCh(__half2* __restrict__ sAmp, int cpad, const __half2* amp) {
  __half2* p = sAmp + cpad;
  #pragma unroll
  for (int g = 0; g < 8; g++) {
    F4H u;
    #pragma unroll
    for (int c = 0; c < 4; c++) u.h[c] = amp[4 * g + c];
    *reinterpret_cast<float4*>(p + 1152 * g) = u.f;
  }
}

// ---- fp32 register-bit FWHT (S0 only)
template<int KB>
__device__ __forceinline__ void fwht_bit(float2* amp) {
  #pragma unroll
  for (int j = 0; j < NAMP; j++) if (!(j & (1 << KB))) {
    int j1 = j | (1 << KB);
    float2 a0 = amp[j], a1 = amp[j1];
    amp[j]  = f2add(a0, a1);
    amp[j1] = f2sub(a0, a1);
  }
}
// ---- fp16 register-bit gates (R0/R6-verified)
template<int KB>
__device__ __forceinline__ void fwht_bitH(__half2* amp) {
  #pragma unroll
  for (int j = 0; j < NAMP; j++) if (!(j & (1 << KB))) {
    int j1 = j | (1 << KB);
    __half2 a0 = amp[j], a1 = amp[j1];
    amp[j]  = __hadd2(a0, a1);
    amp[j1] = __hsub2(a0, a1);
  }
}
template<int KB>
__device__ __forceinline__ void applyRyH(__half2* amp, __half2 nta, __half2 sa) {
  #pragma unroll
  for (int j = 0; j < NAMP; j++) if (!(j & (1 << KB))) {
    int j1 = j | (1 << KB);
    amp[j]  = __hfma2(nta, amp[j1], amp[j]);
    amp[j1] = __hfma2(sa,  amp[j],  amp[j1]);
    amp[j]  = __hfma2(nta, amp[j1], amp[j]);
  }
}
// ---- fp16 lane-bit gates (R1/R3/R6-verified math)
template<int MASK>
__device__ __forceinline__ void laneRyH(__half2* amp, __half2 c2, __half2 spm) {
  #pragma unroll
  for (int j = 0; j < NAMP; j++) {
    __half2 p = lanePartner<MASK>(amp[j]);
    amp[j] = __hfma2(spm, p, __hmul2(c2, amp[j]));
  }
}
template<int MASK>
__device__ __forceinline__ void laneFwhtH(__half2* amp, __half2 sgn) {
  #pragma unroll
  for (int j = 0; j < NAMP; j++) {
    __half2 p = lanePartner<MASK>(amp[j]);
    amp[j] = __hfma2(sgn, amp[j], p);
  }
}

// ---- feature diagonal, H coords (R6 verbatim: base w[5+k] over t bits,
//      tree over window bitpos 0..4); INIT writes unit phase
template<bool INIT>
__device__ __forceinline__ void featureDiagH(float2* amp,
                                             const float* __restrict__ wXp,
                                             const float* __restrict__ wAp,
                                             const float* __restrict__ consp, int t) {
  float u[NAMP], v[NAMP];
  float ub = consp[0], vb = consp[1];
  #pragma unroll
  for (int k = 0; k < 8; k++) if ((t >> k) & 1) { ub += wXp[5 + k]; vb += wAp[5 + k]; }
  u[0] = ub; v[0] = vb;
  #pragma unroll
  for (int k = 0; k < 5; k++) {
    float wu = wXp[k], wv = wAp[k];
    #pragma unroll
    for (int m = 0; m < (1 << k); m++) {
      u[m | (1 << k)] = u[m] + wu;
      v[m | (1 << k)] = v[m] + wv;
    }
  }
  float A2 = consp[2];
  #pragma unroll
  for (int j = 0; j < NAMP; j++) {
    float phi = u[j] + 0.5f * (v[j] * v[j] - A2);
    float sn, cs; rsincos(phi, &sn, &cs);
    if constexpr (INIT) amp[j] = make_float2(cs, sn);
    else                amp[j] = cphase(amp[j], cs, sn);
  }
}

// ---- feature diagonal, C coords: base over ic bits 2..9 (w[2..9]),
//      tree over window bitpos {0,1,10,11,12}
__device__ __forceinline__ void featureDiagC(float2* amp,
                                             const float* __restrict__ wXp,
                                             const float* __restrict__ wAp,
                                             const float* __restrict__ consp, int ic) {
  float u[NAMP], v[NAMP];
  float ub = consp[0], vb = consp[1];
  #pragma unroll
  for (int k = 2; k <= 9; k++) if ((ic >> k) & 1) { ub += wXp[k]; vb += wAp[k]; }
  u[0] = ub; v[0] = vb;
  constexpr int P[5] = {0, 1, 10, 11, 12};
  #pragma unroll
  for (int k = 0; k < 5; k++) {
    float wu = wXp[P[k]], wv = wAp[P[k]];
    #pragma unroll
    for (int m = 0; m < (1 << k); m++) {
      u[m | (1 << k)] = u[m] + wu;
      v[m | (1 << k)] = v[m] + wv;
    }
  }
  float A2 = consp[2];
  #pragma unroll
  for (int j = 0; j < NAMP; j++) {
    float phi = u[j] + 0.5f * (v[j] * v[j] - A2);
    float sn, cs; rsincos(phi, &sn, &cs);
    amp[j] = cphase(amp[j], cs, sn);
  }
}

// ---- Rz_l + ENT diagonal, H coords (R6 applyDiagH verbatim; window i0-i4).
__device__ __forceinline__ void applyDiagH(float2* amp,
                                           const float* __restrict__ wb,
                                           const float* __restrict__ eR,
                                           const float* __restrict__ eI,
                                           float bias, int t) {
  float base = bias;
  #pragma unroll
  for (int k = 0; k < 8; k++) base += ((t >> k) & 1) ? wb[5 + k] : 0.0f;
  float2 c[16];
  { float sn, cs; rsincos(base, &sn, &cs);
    float sg = (__popc(t & (t >> 1)) & 1) ? -1.0f : 1.0f;
    c[0] = make_float2(cs * sg, sn * sg); }
  #pragma unroll
  for (int k = 0; k < 4; k++) {
    float2 ep = make_float2(eR[k], eI[k]);
    float2 em = make_float2(-ep.x, -ep.y);
    #pragma unroll
    for (int m = 0; m < (1 << k); m++) {
      bool neg = (k >= 1) && ((m >> (k - 1)) & 1);   // window pair (k-1,k)
      c[m | (1 << k)] = cmul(c[m], neg ? em : ep);
    }
  }
  #pragma unroll
  for (int j = 0; j < 16; j++) amp[j] = cphase(amp[j], c[j].x, c[j].y);
  float2 e4 = make_float2(eR[4], eI[4]);
  if (t & 1) { e4.x = -e4.x; e4.y = -e4.y; }         // boundary pair (4,5)
  float2 e4m = make_float2(-e4.x, -e4.y);
  #pragma unroll
  for (int j = 16; j < 32; j++) {
    float2 cc = cmul(c[j - 16], ((j >> 3) & 1) ? e4m : e4);  // pair (3,4)
    amp[j] = cphase(amp[j], cc.x, cc.y);
  }
}

// ---- Rz_l + ENT diagonal, C coords (window {0,1,10,11,12}); sign-folded:
//  pairs inside ic (2,3)..(8,9) -> c[0]; boundary (1,2) -> e1 sign by ic2;
//  boundary (9,10) -> e10 sign by ic9; window pairs (0,1) at k=1/m0,
//  (10,11) at k=3/m2, (11,12) at hi-fold/m3. Hand-verified on 6 cases.
__device__ __forceinline__ void applyDiagC(float2* amp,
                                           const float* __restrict__ wb,
                                           const float* __restrict__ eR,
                                           const float* __restrict__ eI,
                                           float bias, int ic) {
  float base = bias;
  #pragma unroll
  for (int k = 2; k <= 9; k++) base += ((ic >> k) & 1) ? wb[k] : 0.0f;
  float2 c[16];
  { float sn, cs; rsincos(base, &sn, &cs);
    float sg = (__popc(ic & (ic >> 1)) & 1) ? -1.0f : 1.0f;
    c[0] = make_float2(cs * sg, sn * sg); }
  { float2 e0 = make_float2(eR[0], eI[0]);           // i0: no boundary
    c[1] = cmul(c[0], e0); }
  { float2 e1 = make_float2(eR[1], eI[1]);
    if ((ic >> 2) & 1) { e1.x = -e1.x; e1.y = -e1.y; }  // boundary (1,2)
    float2 e1m = make_float2(-e1.x, -e1.y);
    c[2] = cmul(c[0], e1);
    c[3] = cmul(c[1], e1m); }                        // pair (0,1): m bit0
  { float2 e2 = make_float2(eR[10], eI[10]);
    if ((ic >> 9) & 1) { e2.x = -e2.x; e2.y = -e2.y; }  // boundary (9,10)
    #pragma unroll
    for (int m = 0; m < 4; m++) c[m | 4] = cmul(c[m], e2); }
  { float2 e3 = make_float2(eR[11], eI[11]);
    float2 e3m = make_float2(-e3.x, -e3.y);
    #pragma unroll
    for (int m = 0; m < 8; m++)
      c[m | 8] = cmul(c[m], ((m >> 2) & 1) ? e3m : e3); }  // pair (10,11)
  #pragma unroll
  for (int j = 0; j < 16; j++) amp[j] = cphase(amp[j], c[j].x, c[j].y);
  float2 e4  = make_float2(eR[12], eI[12]);
  float2 e4m = make_float2(-e4.x, -e4.y);
  #pragma unroll
  for (int j = 16; j < 32; j++) {
    float2 cc = cmul(c[j - 16], ((j >> 3) & 1) ? e4m : e4);  // pair (11,12)
    amp[j] = cphase(amp[j], cc.x, cc.y);
  }
}

// H gates of one layer: reg q12..q8 + DPP q7(m1), q6(m2), q4(m8); all fp16
__device__ __forceinline__ void gatesH(__half2* ampH,
                                       const __half2* __restrict__ hNTA,
                                       const __half2* __restrict__ hSA,
                                       const __half2* __restrict__ hC2,
                                       const __half2* __restrict__ hS2,
                                       int g0, int lane) {
  { __half2 s2 = hS2[g0 + 7]; laneRyH<1>(ampH, hC2[g0 + 7], (lane & 1) ? s2 : __hneg2(s2)); }
  { __half2 s2 = hS2[g0 + 6]; laneRyH<2>(ampH, hC2[g0 + 6], (lane & 2) ? s2 : __hneg2(s2)); }
  { __half2 s2 = hS2[g0 + 4]; laneRyH<8>(ampH, hC2[g0 + 4], (lane & 8) ? s2 : __hneg2(s2)); }
  applyRyH<0>(ampH, hNTA[g0 + 12], hSA[g0 + 12]);
  applyRyH<1>(ampH, hNTA[g0 + 11], hSA[g0 + 11]);
  applyRyH<2>(ampH, hNTA[g0 + 10], hSA[g0 + 10]);
  applyRyH<3>(ampH, hNTA[g0 + 9],  hSA[g0 + 9]);
  applyRyH<4>(ampH, hNTA[g0 + 8],  hSA[g0 + 8]);
}
// C gates of one layer: reg q2(j2), q1(j3), q0(j4) + DPP q5(m1), q3(m2); fp16
__device__ __forceinline__ void gatesC(__half2* ampH,
                                       const __half2* __restrict__ hNTA,
                                       const __half2* __restrict__ hSA,
                                       const __half2* __restrict__ hC2,
                                       const __half2* __restrict__ hS2,
                                       int g0, int lane) {
  { __half2 s2 = hS2[g0 + 5]; laneRyH<1>(ampH, hC2[g0 + 5], (lane & 1) ? s2 : __hneg2(s2)); }
  { __half2 s2 = hS2[g0 + 3]; laneRyH<2>(ampH, hC2[g0 + 3], (lane & 2) ? s2 : __hneg2(s2)); }
  applyRyH<2>(ampH, hNTA[g0 + 2], hSA[g0 + 2]);
  applyRyH<3>(ampH, hNTA[g0 + 1], hSA[g0 + 1]);
  applyRyH<4>(ampH, hNTA[g0 + 0], hSA[g0 + 0]);
}

// (256,1): lifted VGPR cap avoids the spill cliff; grid 512 -> 2 blocks/CU.
__global__ __launch_bounds__(NT, 1) void qc_kernel(
    const float* __restrict__ xin,
    const float* __restrict__ thin,
    const float* __restrict__ bin,
    float* __restrict__ out) {
  __shared__ alignas(16) __half2 sAmp[NSLOT];
  __shared__ __half2 hNTA[65], hSA[65];   // fp16 shear (-ta,-ta),(sa,sa), l*13+q
  __shared__ __half2 hC2[65], hS2[65];    // fp16 rotation (c,c),(s,s), l*13+q
  __shared__ float gBbit[65];             // Rz b by [l*13 + bitpos], bitpos = 12-q
  __shared__ float eBr[65], eBi[65];      // cos(b), sin(b) by [l*13 + bitpos]
  __shared__ float wX[13], wA[13];        // -2x, -2a by bitpos
  __shared__ float cons[8];               // 0:X 1:A 2:A2 3..7:-0.5*sum b_l
  __shared__ float red[NT / 64];

  const int t = threadIdx.x;
  const int lane = t & 63;
  const int ic = fC(t);
  const int cpad = ic + 4 * (ic >> 5);
  const int b = blockIdx.x;

  if (t < NQ) {
    float xq = xin[b * NQ + t];
    float aq = PI_F - xq;
    wX[12 - t] = -2.0f * xq;
    wA[12 - t] = -2.0f * aq;
  }
  if (t < 65) {
    float av = thin[2 * t];
    float bv = thin[2 * t + 1];
    float ca = cosf(0.5f * av);
    float sa = sinf(0.5f * av);
    float ta = sa / (1.0f + ca);
    hNTA[t] = __float2half2_rn(-ta);
    hSA[t]  = __float2half2_rn(sa);
    hC2[t]  = __float2half2_rn(ca);
    hS2[t]  = __float2half2_rn(sa);
    int l = t / NQ, q = t % NQ;
    int s = l * NQ + (12 - q);
    gBbit[s] = bv;
    eBr[s] = cosf(bv);
    eBi[s] = sinf(bv);
  }
  __syncthreads();
  if (t == 0) {
    float X = 0.f, A = 0.f, A2 = 0.f;
    for (int p = 0; p < NQ; p++) {
      float xq = -0.5f * wX[p], aq = -0.5f * wA[p];
      X += xq; A += aq; A2 += aq * aq;
    }
    cons[0] = X; cons[1] = A; cons[2] = A2;
    for (int l = 0; l < 5; l++) {
      float s = 0.f;
      for (int p = 0; p < NQ; p++) s += gBbit[l * NQ + p];
      cons[3 + l] = -0.5f * s;
    }
  }
  __syncthreads();

  const __half2 P1 = __float2half2_rn(1.0f), M1 = __float2half2_rn(-1.0f);

  // ---- S0 [H]: init psi = exp(i*phi1); FWHT i0..i4 (reg fp32),
  //              i5(m1), i6(m2), i8(m8) DPP + i7(m4), i9(m16) shfl (fp16)
  {
    float2 ampF[NAMP];
    featureDiagH<true>(ampF, wX, wA, cons, t);
    fwht_bit<0>(ampF); fwht_bit<1>(ampF); fwht_bit<2>(ampF);
    fwht_bit<3>(ampF); fwht_bit<4>(ampF);
    __half2 ampH[NAMP];
    #pragma unroll
    for (int j = 0; j < NAMP; j++) ampH[j] = __float22half2_rn(ampF[j]);
    laneFwhtH<1>(ampH,  (lane & 1)  ? M1 : P1);   // i5
    laneFwhtH<2>(ampH,  (lane & 2)  ? M1 : P1);   // i6
    laneFwhtH<8>(ampH,  (lane & 8)  ? M1 : P1);   // i8
    laneFwhtH<4>(ampH,  (lane & 4)  ? M1 : P1);   // i7 (shfl, FWHT-only)
    laneFwhtH<16>(ampH, (lane & 16) ? M1 : P1);   // i9 (shfl, FWHT-only)
    storeHh(sAmp, t, ampH);
  }
  __syncthreads();

  // ---- S1 [C]: FWHT i10,i11,i12 (reg fp16); featDiag2 (fp32); L0 C-gates
  {
    __half2 ampH[NAMP];
    loadCh(sAmp, cpad, ampH);
    fwht_bitH<2>(ampH); fwht_bitH<3>(ampH); fwht_bitH<4>(ampH);
    float2 ampF[NAMP];
    #pragma unroll
    for (int j = 0; j < NAMP; j++) ampF[j] = __half22float2(ampH[j]);
    featureDiagC(ampF, wX, wA, cons, ic);
    #pragma unroll
    for (int j = 0; j < NAMP; j++) ampH[j] = __float22half2_rn(ampF[j]);
    gatesC(ampH, hNTA, hSA, hC2, hS2, 0, lane);
    storeCh(sAmp, cpad, ampH);
  }
  __syncthreads();

  // ---- S2/S4 [H] + S3/S5 [C]
  for (int l = 0; l < 4; l += 2) {
    const int ga = l * NQ, gb = ga + NQ, gc = gb + NQ;
    // H phase: layer l H-gates, diag_l, layer l+1 H-gates
    {
      __half2 ampH[NAMP];
      loadHh(sAmp, t, ampH);
      gatesH(ampH, hNTA, hSA, hC2, hS2, ga, lane);
      float2 ampF[NAMP];
      #pragma unroll
      for (int j = 0; j < NAMP; j++) ampF[j] = __half22float2(ampH[j]);
      applyDiagH(ampF, gBbit + ga, eBr + ga, eBi + ga, cons[3 + l], t);
      #pragma unroll
      for (int j = 0; j < NAMP; j++) ampH[j] = __float22half2_rn(ampF[j]);
      gatesH(ampH, hNTA, hSA, hC2, hS2, gb, lane);
      storeHh(sAmp, t, ampH);
    }
    __syncthreads();
    // C phase: layer l+1 C-gates, diag_{l+1}, layer l+2 C-gates
    {
      __half2 ampH[NAMP];
      loadCh(sAmp, cpad, ampH);
      gatesC(ampH, hNTA, hSA, hC2, hS2, gb, lane);
      float2 ampF[NAMP];
      #pragma unroll
      for (int j = 0; j < NAMP; j++) ampF[j] = __half22float2(ampH[j]);
      applyDiagC(ampF, gBbit + gb, eBr + gb, eBi + gb, cons[3 + l + 1], ic);
      #pragma unroll
      for (int j = 0; j < NAMP; j++) ampH[j] = __float22half2_rn(ampF[j]);
      gatesC(ampH, hNTA, hSA, hC2, hS2, gc, lane);
      storeCh(sAmp, cpad, ampH);
    }
    __syncthreads();
  }

  // ---- S6 [H]: layer 4 H-gates; readout (trailing Rz_4 invisible)
  float acc = 0.0f;
  {
    const int ga = 4 * NQ;
    __half2 ampH[NAMP];
    loadHh(sAmp, t, ampH);
    gatesH(ampH, hNTA, hSA, hC2, hS2, ga, lane);
    int pt = __popc(t) & 1;
    #pragma unroll
    for (int j = 0; j < NAMP; j++) {
      float2 a = __half22float2(ampH[j]);
      float p2 = fmaf(a.x, a.x, a.y * a.y);
      acc += ((pt + __popc(j)) & 1) ? -p2 : p2;
    }
  }

  // block reduction (raw scale 2^26)
  #pragma unroll
  for (int off = 32; off > 0; off >>= 1) acc += __shfl_down(acc, off, 64);
  if ((t & 63) == 0) red[t >> 6] = acc;
  __syncthreads();
  if (t == 0) {
    float total = red[0] + red[1] + red[2] + red[3];
    float logit = total * (1.0f / 67108864.0f) + bin[0];
    out[b * 2 + 0] = -logit;
    out[b * 2 + 1] = logit;
  }
}

extern "C" void kernel_launch(void* const* d_in, const int* in_sizes, int n_in,
                              void* d_out, int out_size, void* d_ws, size_t ws_size,
                              hipStream_t stream) {
  const float* x  = (const float*)d_in[0];
  const float* th = (const float*)d_in[1];
  const float* bi = (const float*)d_in[2];
  float* out = (float*)d_out;
  int B = in_sizes[0] / NQ;   // 512
  qc_kernel<<<B, NT, 0, stream>>>(x, th, bi, out);
}

// Round 12
// 89.943 us; speedup vs baseline: 1.0986x; 1.0040x over previous
//
#include <hip/hip_runtime.h>
#include <hip/hip_fp16.h>

#define NQ   13
#define DIM  8192
#define PI_F 3.14159265358979323846f
#define NT   256     // 4 waves/block; grid 512 -> 2 blocks/CU
#define NAMP 32      // amplitudes per thread (5-bit register window)
#define NSLOT 9280   // L(8191)=9271 under the new pad, rounded up

// Global LDS layout: L(i) = i + 4*(i>>5) + 4*(i>>9)  (half2 slots).
// The +4*(i>>9) term makes i9 bank-ACTIVE (+512 slots -> +580 = +4 banks),
// fixing R8's 593K conflicts (t1-lane pairs collided at +576 = 0 mod 32).
// Bank audits (by hand, per wave):
//   H: group(l) = (l%8 + (l>>4)) mod 8 -> 8 lanes/group = b128 floor.
//   C: group = f(t2..t5: 2/group) + 4*t0 + 1*t1 mod 8 -> uniform 8/group.
// Pattern H: i = (t<<5)|j. reg j = i0..i4 (q12..q8); lane t0,t1,t3 ->
//   i5,i6,i8 (q7,q6,q4) DPP masks 1,2,8; t2,t4 -> i7,i9 shfl (FWHT only);
//   t5 -> i10 (ungated in H); wave t6,t7 -> i11,i12. 32 contiguous slots
//   -> 8x b128.
// Pattern C: i = (g<<10)|fC(t)|c, amp j = (g<<2)|c. reg j2,j3,j4 =
//   i10,i11,i12 (q2,q1,q0); j0,j1 = i0,i1 (held, gated in H). Lane t0,t1
//   -> i7,i9 (q5,q3) DPP masks 1,2. fC: t0->i7, t1->i9, t2..t6->i2..i6,
//   t7->i8. 8 runs of 4 slots -> 8x b128 at stride 1160.
__device__ __forceinline__ int baseH(int t) { return 36 * t + 4 * (t >> 4); }
__device__ __forceinline__ int fC(int t) {
  return ((t & 1) << 7) | (((t >> 1) & 1) << 9) | (((t >> 2) & 0x1F) << 2)
       | (((t >> 7) & 1) << 8);
}

union F4H { float4 f; __half2 h[4]; };

__device__ __forceinline__ void rsincos(float x, float* s, float* c) {
  const float INV2PI = 0.15915494309189535f;
  const float TWOPI  = 6.283185307179586f;
  float r = x * INV2PI;
  r -= rintf(r);
  float ang = r * TWOPI;
  *s = __sinf(ang);
  *c = __cosf(ang);
}

// ---- fp32 helpers
__device__ __forceinline__ float2 cphase(float2 v, float cs, float sn) {
  return make_float2(fmaf(cs, v.x, -sn * v.y), fmaf(cs, v.y, sn * v.x));
}
__device__ __forceinline__ float2 cmul(float2 a, float2 b) {
  return make_float2(fmaf(a.x, b.x, -a.y * b.y), fmaf(a.x, b.y, a.y * b.x));
}

// ---- cross-lane partner: DPP masks 1,2 (quad_perm), 8 (row_ror:8) — all
// proven R3/R5/R6; masks 4,16 via shfl_xor (proven R7; FWHT-only here).
template<int MASK>
__device__ __forceinline__ __half2 lanePartner(__half2 v) {
  union { __half2 h; int i; } u, r; u.h = v;
  if constexpr (MASK == 1)
    r.i = __builtin_amdgcn_update_dpp(u.i, u.i, 0xB1, 0xF, 0xF, false);  // [1,0,3,2]
  else if constexpr (MASK == 2)
    r.i = __builtin_amdgcn_update_dpp(u.i, u.i, 0x4E, 0xF, 0xF, false);  // [2,3,0,1]
  else if constexpr (MASK == 8)
    r.i = __builtin_amdgcn_update_dpp(u.i, u.i, 0x128, 0xF, 0xF, false); // row_ror:8
  else
    r.i = __shfl_xor(u.i, MASK, 64);
  return r.h;
}

// ---- LDS access, H pattern (8x b128)
__device__ __forceinline__ void loadHh(const __half2* __restrict__ sAmp, int t, __half2* amp) {
  const __half2* p = sAmp + baseH(t);
  #pragma unroll
  for (int k = 0; k < 8; k++) {
    F4H u; u.f = *reinterpret_cast<const float4*>(p + 4 * k);
    #pragma unroll
    for (int c = 0; c < 4; c++) amp[4 * k + c] = u.h[c];
  }
}
__device__ __forceinline__ void storeHh(__half2* __restrict__ sAmp, int t, const __half2* amp) {
  __half2* p = sAmp + baseH(t);
  #pragma unroll
  for (int k = 0; k < 8; k++) {
    F4H u;
    #pragma unroll
    for (int c = 0; c < 4; c++) u.h[c] = amp[4 * k + c];
    *reinterpret_cast<float4*>(p + 4 * k) = u.f;
  }
}
// ---- LDS access, C pattern (8x b128 at stride 1160, base cpad = L(fC(t)))
__device__ __forceinline__ void loadCh(const __half2* __restrict__ sAmp, int cpad, __half2* amp) {
  const __half2* p = sAmp + cpad;
  #pragma unroll
  for (int g = 0; g < 8; g++) {
    F4H u; u.f = *reinterpret_cast<const float4*>(p + 1160 * g);
    #pragma unroll
    for (int c = 0; c < 4; c++) amp[4 * g + c] = u.h[c];
  }
}
__device__ __forceinline__ void storeCh(__half2* __restrict__ sAmp, int cpad, const __half2* amp) {
  __half2* p = sAmp + cpad;
  #pragma unroll
  for (int g = 0; g < 8; g++) {
    F4H u;
    #pragma unroll
    for (int c = 0; c < 4; c++) u.h[c] = amp[4 * g + c];
    *reinterpret_cast<float4*>(p + 1160 * g) = u.f;
  }
}

// ---- fp16 register-bit gates (R0/R6-verified)
template<int KB>
__device__ __forceinline__ void fwht_bitH(__half2* amp) {
  #pragma unroll
  for (int j = 0; j < NAMP; j++) if (!(j & (1 << KB))) {
    int j1 = j | (1 << KB);
    __half2 a0 = amp[j], a1 = amp[j1];
    amp[j]  = __hadd2(a0, a1);
    amp[j1] = __hsub2(a0, a1);
  }
}
template<int KB>
__device__ __forceinline__ void applyRyH(__half2* amp, __half2 nta, __half2 sa) {
  #pragma unroll
  for (int j = 0; j < NAMP; j++) if (!(j & (1 << KB))) {
    int j1 = j | (1 << KB);
    amp[j]  = __hfma2(nta, amp[j1], amp[j]);
    amp[j1] = __hfma2(sa,  amp[j],  amp[j1]);
    amp[j]  = __hfma2(nta, amp[j1], amp[j]);
  }
}
// ---- fp16 lane-bit gates (R1/R3/R6-verified math)
template<int MASK>
__device__ __forceinline__ void laneRyH(__half2* amp, __half2 c2, __half2 spm) {
  #pragma unroll
  for (int j = 0; j < NAMP; j++) {
    __half2 p = lanePartner<MASK>(amp[j]);
    amp[j] = __hfma2(spm, p, __hmul2(c2, amp[j]));
  }
}
template<int MASK>
__device__ __forceinline__ void laneFwhtH(__half2* amp, __half2 sgn) {
  #pragma unroll
  for (int j = 0; j < NAMP; j++) {
    __half2 p = lanePartner<MASK>(amp[j]);
    amp[j] = __hfma2(sgn, amp[j], p);
  }
}

// ---- feature diagonal, H coords (base w[5+k] over t bits, tree over
//      window bitpos 0..4); INIT writes unit phase
template<bool INIT>
__device__ __forceinline__ void featureDiagH(float2* amp,
                                             const float* __restrict__ wXp,
                                             const float* __restrict__ wAp,
                                             const float* __restrict__ consp, int t) {
  float u[NAMP], v[NAMP];
  float ub = consp[0], vb = consp[1];
  #pragma unroll
  for (int k = 0; k < 8; k++) if ((t >> k) & 1) { ub += wXp[5 + k]; vb += wAp[5 + k]; }
  u[0] = ub; v[0] = vb;
  #pragma unroll
  for (int k = 0; k < 5; k++) {
    float wu = wXp[k], wv = wAp[k];
    #pragma unroll
    for (int m = 0; m < (1 << k); m++) {
      u[m | (1 << k)] = u[m] + wu;
      v[m | (1 << k)] = v[m] + wv;
    }
  }
  float A2 = consp[2];
  #pragma unroll
  for (int j = 0; j < NAMP; j++) {
    float phi = u[j] + 0.5f * (v[j] * v[j] - A2);
    float sn, cs; rsincos(phi, &sn, &cs);
    if constexpr (INIT) amp[j] = make_float2(cs, sn);
    else                amp[j] = cphase(amp[j], cs, sn);
  }
}

// ---- feature diagonal, C coords: base over ic bits 2..9 (w[2..9]),
//      tree over window bitpos {0,1,10,11,12}
__device__ __forceinline__ void featureDiagC(float2* amp,
                                             const float* __restrict__ wXp,
                                             const float* __restrict__ wAp,
                                             const float* __restrict__ consp, int ic) {
  float u[NAMP], v[NAMP];
  float ub = consp[0], vb = consp[1];
  #pragma unroll
  for (int k = 2; k <= 9; k++) if ((ic >> k) & 1) { ub += wXp[k]; vb += wAp[k]; }
  u[0] = ub; v[0] = vb;
  constexpr int P[5] = {0, 1, 10, 11, 12};
  #pragma unroll
  for (int k = 0; k < 5; k++) {
    float wu = wXp[P[k]], wv = wAp[P[k]];
    #pragma unroll
    for (int m = 0; m < (1 << k); m++) {
      u[m | (1 << k)] = u[m] + wu;
      v[m | (1 << k)] = v[m] + wv;
    }
  }
  float A2 = consp[2];
  #pragma unroll
  for (int j = 0; j < NAMP; j++) {
    float phi = u[j] + 0.5f * (v[j] * v[j] - A2);
    float sn, cs; rsincos(phi, &sn, &cs);
    amp[j] = cphase(amp[j], cs, sn);
  }
}

// ---- Rz_l + ENT diagonal, H coords (window i0-i4; R6/R8-verified)
__device__ __forceinline__ void applyDiagH(float2* amp,
                                           const float* __restrict__ wb,
                                           const float* __restrict__ eR,
                                           const float* __restrict__ eI,
                                           float bias, int t) {
  float base = bias;
  #pragma unroll
  for (int k = 0; k < 8; k++) base += ((t >> k) & 1) ? wb[5 + k] : 0.0f;
  float2 c[16];
  { float sn, cs; rsincos(base, &sn, &cs);
    float sg = (__popc(t & (t >> 1)) & 1) ? -1.0f : 1.0f;
    c[0] = make_float2(cs * sg, sn * sg); }
  #pragma unroll
  for (int k = 0; k < 4; k++) {
    float2 ep = make_float2(eR[k], eI[k]);
    float2 em = make_float2(-ep.x, -ep.y);
    #pragma unroll
    for (int m = 0; m < (1 << k); m++) {
      bool neg = (k >= 1) && ((m >> (k - 1)) & 1);   // window pair (k-1,k)
      c[m | (1 << k)] = cmul(c[m], neg ? em : ep);
    }
  }
  #pragma unroll
  for (int j = 0; j < 16; j++) amp[j] = cphase(amp[j], c[j].x, c[j].y);
  float2 e4 = make_float2(eR[4], eI[4]);
  if (t & 1) { e4.x = -e4.x; e4.y = -e4.y; }         // boundary pair (4,5)
  float2 e4m = make_float2(-e4.x, -e4.y);
  #pragma unroll
  for (int j = 16; j < 32; j++) {
    float2 cc = cmul(c[j - 16], ((j >> 3) & 1) ? e4m : e4);  // pair (3,4)
    amp[j] = cphase(amp[j], cc.x, cc.y);
  }
}

// ---- Rz_l + ENT diagonal, C coords (window {0,1,10,11,12}; R8-verified)
__device__ __forceinline__ void applyDiagC(float2* amp,
                                           const float* __restrict__ wb,
                                           const float* __restrict__ eR,
                                           const float* __restrict__ eI,
                                           float bias, int ic) {
  float base = bias;
  #pragma unroll
  for (int k = 2; k <= 9; k++) base += ((ic >> k) & 1) ? wb[k] : 0.0f;
  float2 c[16];
  { float sn, cs; rsincos(base, &sn, &cs);
    float sg = (__popc(ic & (ic >> 1)) & 1) ? -1.0f : 1.0f;
    c[0] = make_float2(cs * sg, sn * sg); }
  { float2 e0 = make_float2(eR[0], eI[0]);           // i0: no boundary
    c[1] = cmul(c[0], e0); }
  { float2 e1 = make_float2(eR[1], eI[1]);
    if ((ic >> 2) & 1) { e1.x = -e1.x; e1.y = -e1.y; }  // boundary (1,2)
    float2 e1m = make_float2(-e1.x, -e1.y);
    c[2] = cmul(c[0], e1);
    c[3] = cmul(c[1], e1m); }                        // pair (0,1): m bit0
  { float2 e2 = make_float2(eR[10], eI[10]);
    if ((ic >> 9) & 1) { e2.x = -e2.x; e2.y = -e2.y; }  // boundary (9,10)
    #pragma unroll
    for (int m = 0; m < 4; m++) c[m | 4] = cmul(c[m], e2); }
  { float2 e3 = make_float2(eR[11], eI[11]);
    float2 e3m = make_float2(-e3.x, -e3.y);
    #pragma unroll
    for (int m = 0; m < 8; m++)
      c[m | 8] = cmul(c[m], ((m >> 2) & 1) ? e3m : e3); }  // pair (10,11)
  #pragma unroll
  for (int j = 0; j < 16; j++) amp[j] = cphase(amp[j], c[j].x, c[j].y);
  float2 e4  = make_float2(eR[12], eI[12]);
  float2 e4m = make_float2(-e4.x, -e4.y);
  #pragma unroll
  for (int j = 16; j < 32; j++) {
    float2 cc = cmul(c[j - 16], ((j >> 3) & 1) ? e4m : e4);  // pair (11,12)
    amp[j] = cphase(amp[j], cc.x, cc.y);
  }
}

// H gates of one layer: reg q12..q8 + DPP q7(m1), q6(m2), q4(m8); all fp16
__device__ __forceinline__ void gatesH(__half2* ampH,
                                       const __half2* __restrict__ hNTA,
                                       const __half2* __restrict__ hSA,
                                       const __half2* __restrict__ hC2,
                                       const __half2* __restrict__ hS2,
                                       int g0, int lane) {
  { __half2 s2 = hS2[g0 + 7]; laneRyH<1>(ampH, hC2[g0 + 7], (lane & 1) ? s2 : __hneg2(s2)); }
  { __half2 s2 = hS2[g0 + 6]; laneRyH<2>(ampH, hC2[g0 + 6], (lane & 2) ? s2 : __hneg2(s2)); }
  { __half2 s2 = hS2[g0 + 4]; laneRyH<8>(ampH, hC2[g0 + 4], (lane & 8) ? s2 : __hneg2(s2)); }
  applyRyH<0>(ampH, hNTA[g0 + 12], hSA[g0 + 12]);
  applyRyH<1>(ampH, hNTA[g0 + 11], hSA[g0 + 11]);
  applyRyH<2>(ampH, hNTA[g0 + 10], hSA[g0 + 10]);
  applyRyH<3>(ampH, hNTA[g0 + 9],  hSA[g0 + 9]);
  applyRyH<4>(ampH, hNTA[g0 + 8],  hSA[g0 + 8]);
}
// C gates of one layer: reg q2(j2), q1(j3), q0(j4) + DPP q5(m1), q3(m2); fp16
__device__ __forceinline__ void gatesC(__half2* ampH,
                                       const __half2* __restrict__ hNTA,
                                       const __half2* __restrict__ hSA,
                                       const __half2* __restrict__ hC2,
                                       const __half2* __restrict__ hS2,
                                       int g0, int lane) {
  { __half2 s2 = hS2[g0 + 5]; laneRyH<1>(ampH, hC2[g0 + 5], (lane & 1) ? s2 : __hneg2(s2)); }
  { __half2 s2 = hS2[g0 + 3]; laneRyH<2>(ampH, hC2[g0 + 3], (lane & 2) ? s2 : __hneg2(s2)); }
  applyRyH<2>(ampH, hNTA[g0 + 2], hSA[g0 + 2]);
  applyRyH<3>(ampH, hNTA[g0 + 1], hSA[g0 + 1]);
  applyRyH<4>(ampH, hNTA[g0 + 0], hSA[g0 + 0]);
}

// (256,1): lifted VGPR cap avoids the spill cliff; grid 512 -> 2 blocks/CU.
__global__ __launch_bounds__(NT, 1) void qc_kernel(
    const float* __restrict__ xin,
    const float* __restrict__ thin,
    const float* __restrict__ bin,
    float* __restrict__ out) {
  __shared__ alignas(16) __half2 sAmp[NSLOT];
  __shared__ __half2 hNTA[65], hSA[65];   // fp16 shear (-ta,-ta),(sa,sa), l*13+q
  __shared__ __half2 hC2[65], hS2[65];    // fp16 rotation (c,c),(s,s), l*13+q
  __shared__ float gBbit[65];             // Rz b by [l*13 + bitpos], bitpos = 12-q
  __shared__ float eBr[65], eBi[65];      // cos(b), sin(b) by [l*13 + bitpos]
  __shared__ float wX[13], wA[13];        // -2x, -2a by bitpos
  __shared__ float cons[8];               // 0:X 1:A 2:A2 3..7:-0.5*sum b_l
  __shared__ float red[NT / 64];

  const int t = threadIdx.x;
  const int lane = t & 63;
  const int ic = fC(t);
  const int cpad = ic + 4 * (ic >> 5) + 4 * (ic >> 9);
  const int b = blockIdx.x;

  if (t < NQ) {
    float xq = xin[b * NQ + t];
    float aq = PI_F - xq;
    wX[12 - t] = -2.0f * xq;
    wA[12 - t] = -2.0f * aq;
  }
  if (t < 65) {
    float av = thin[2 * t];
    float bv = thin[2 * t + 1];
    float ca = cosf(0.5f * av);
    float sa = sinf(0.5f * av);
    float ta = sa / (1.0f + ca);
    hNTA[t] = __float2half2_rn(-ta);
    hSA[t]  = __float2half2_rn(sa);
    hC2[t]  = __float2half2_rn(ca);
    hS2[t]  = __float2half2_rn(sa);
    int l = t / NQ, q = t % NQ;
    int s = l * NQ + (12 - q);
    gBbit[s] = bv;
    eBr[s] = cosf(bv);
    eBi[s] = sinf(bv);
  }
  __syncthreads();
  if (t == 0) {
    float X = 0.f, A = 0.f, A2 = 0.f;
    for (int p = 0; p < NQ; p++) {
      float xq = -0.5f * wX[p], aq = -0.5f * wA[p];
      X += xq; A += aq; A2 += aq * aq;
    }
    cons[0] = X; cons[1] = A; cons[2] = A2;
    for (int l = 0; l < 5; l++) {
      float s = 0.f;
      for (int p = 0; p < NQ; p++) s += gBbit[l * NQ + p];
      cons[3 + l] = -0.5f * s;
    }
  }
  __syncthreads();

  const __half2 P1 = __float2half2_rn(1.0f), M1 = __float2half2_rn(-1.0f);

  // ---- S0 [H]: init psi = exp(i*phi1) (fp32); ALL FWHT stages fp16:
  //              i0..i4 reg, i5(m1), i6(m2), i8(m8) DPP, i7(m4), i9(m16) shfl
  {
    float2 ampF[NAMP];
    featureDiagH<true>(ampF, wX, wA, cons, t);
    __half2 ampH[NAMP];
    #pragma unroll
    for (int j = 0; j < NAMP; j++) ampH[j] = __float22half2_rn(ampF[j]);
    fwht_bitH<0>(ampH); fwht_bitH<1>(ampH); fwht_bitH<2>(ampH);
    fwht_bitH<3>(ampH); fwht_bitH<4>(ampH);
    laneFwhtH<1>(ampH,  (lane & 1)  ? M1 : P1);   // i5
    laneFwhtH<2>(ampH,  (lane & 2)  ? M1 : P1);   // i6
    laneFwhtH<8>(ampH,  (lane & 8)  ? M1 : P1);   // i8
    laneFwhtH<4>(ampH,  (lane & 4)  ? M1 : P1);   // i7 (shfl, FWHT-only)
    laneFwhtH<16>(ampH, (lane & 16) ? M1 : P1);   // i9 (shfl, FWHT-only)
    storeHh(sAmp, t, ampH);
  }
  __syncthreads();

  // ---- S1 [C]: FWHT i10,i11,i12 (reg fp16); featDiag2 (fp32); L0 C-gates
  {
    __half2 ampH[NAMP];
    loadCh(sAmp, cpad, ampH);
    fwht_bitH<2>(ampH); fwht_bitH<3>(ampH); fwht_bitH<4>(ampH);
    float2 ampF[NAMP];
    #pragma unroll
    for (int j = 0; j < NAMP; j++) ampF[j] = __half22float2(ampH[j]);
    featureDiagC(ampF, wX, wA, cons, ic);
    #pragma unroll
    for (int j = 0; j < NAMP; j++) ampH[j] = __float22half2_rn(ampF[j]);
    gatesC(ampH, hNTA, hSA, hC2, hS2, 0, lane);
    storeCh(sAmp, cpad, ampH);
  }
  __syncthreads();

  // ---- S2/S4 [H] + S3/S5 [C]
  for (int l = 0; l < 4; l += 2) {
    const int ga = l * NQ, gb = ga + NQ, gc = gb + NQ;
    // H phase: layer l H-gates, diag_l, layer l+1 H-gates
    {
      __half2 ampH[NAMP];
      loadHh(sAmp, t, ampH);
      gatesH(ampH, hNTA, hSA, hC2, hS2, ga, lane);
      float2 ampF[NAMP];
      #pragma unroll
      for (int j = 0; j < NAMP; j++) ampF[j] = __half22float2(ampH[j]);
      applyDiagH(ampF, gBbit + ga, eBr + ga, eBi + ga, cons[3 + l], t);
      #pragma unroll
      for (int j = 0; j < NAMP; j++) ampH[j] = __float22half2_rn(ampF[j]);
      gatesH(ampH, hNTA, hSA, hC2, hS2, gb, lane);
      storeHh(sAmp, t, ampH);
    }
    __syncthreads();
    // C phase: layer l+1 C-gates, diag_{l+1}, layer l+2 C-gates
    {
      __half2 ampH[NAMP];
      loadCh(sAmp, cpad, ampH);
      gatesC(ampH, hNTA, hSA, hC2, hS2, gb, lane);
      float2 ampF[NAMP];
      #pragma unroll
      for (int j = 0; j < NAMP; j++) ampF[j] = __half22float2(ampH[j]);
      applyDiagC(ampF, gBbit + gb, eBr + gb, eBi + gb, cons[3 + l + 1], ic);
      #pragma unroll
      for (int j = 0; j < NAMP; j++) ampH[j] = __float22half2_rn(ampF[j]);
      gatesC(ampH, hNTA, hSA, hC2, hS2, gc, lane);
      storeCh(sAmp, cpad, ampH);
    }
    __syncthreads();
  }

  // ---- S6 [H]: layer 4 H-gates; readout (trailing Rz_4 invisible)
  float acc = 0.0f;
  {
    const int ga = 4 * NQ;
    __half2 ampH[NAMP];
    loadHh(sAmp, t, ampH);
    gatesH(ampH, hNTA, hSA, hC2, hS2, ga, lane);
    int pt = __popc(t) & 1;
    #pragma unroll
    for (int j = 0; j < NAMP; j++) {
      float2 a = __half22float2(ampH[j]);
      float p2 = fmaf(a.x, a.x, a.y * a.y);
      acc += ((pt + __popc(j)) & 1) ? -p2 : p2;
    }
  }

  // block reduction (raw scale 2^26)
  #pragma unroll
  for (int off = 32; off > 0; off >>= 1) acc += __shfl_down(acc, off, 64);
  if ((t & 63) == 0) red[t >> 6] = acc;
  __syncthreads();
  if (t == 0) {
    float total = red[0] + red[1] + red[2] + red[3];
    float logit = total * (1.0f / 67108864.0f) + bin[0];
    out[b * 2 + 0] = -logit;
    out[b * 2 + 1] = logit;
  }
}

extern "C" void kernel_launch(void* const* d_in, const int* in_sizes, int n_in,
                              void* d_out, int out_size, void* d_ws, size_t ws_size,
                              hipStream_t stream) {
  const float* x  = (const float*)d_in[0];
  const float* th = (const float*)d_in[1];
  const float* bi = (const float*)d_in[2];
  float* out = (float*)d_out;
  int B = in_sizes[0] / NQ;   // 512
  qc_kernel<<<B, NT, 0, stream>>>(x, th, bi, out);
}